// Round 23
// baseline (66.724 us; speedup 1.0000x reference)
//
#include <hip/hip_runtime.h>

#define DD 256
#define BB 64
#define SS 256                       // H*W
#define K2 2.8853900817779268f      // 2*log2(e)
#define LOG2E 1.4426950408889634f

#if __has_builtin(__builtin_amdgcn_exp2f)
#define EXP2(x) __builtin_amdgcn_exp2f(x)
#else
#define EXP2(x) exp2f(x)
#endif

typedef __attribute__((ext_vector_type(8))) short bf16x8;
typedef __attribute__((ext_vector_type(4))) float f32x4;

static __device__ __forceinline__ float fast_rcp(float x) {
  return __builtin_amdgcn_rcpf(x);
}

// ---- kernel 1: att_r = pe@wo^T + b.  grid (T), block 256. ----
__global__ __launch_bounds__(256) void k_prep(
    const float* __restrict__ wo_w, const float* __restrict__ wo_b,
    float* __restrict__ att_r, int T)
{
  const int tid = threadIdx.x;
  const int t = blockIdx.x;
  if (t >= T) return;
  __shared__ float pe[DD];
  {
    int i = tid >> 1;
    double r = pow(10000.0, -(double)(2*i) / 256.0);
    double ang = (double)t * r;
    pe[tid] = (float)((tid & 1) ? cos(ang) : sin(ang));
  }
  __syncthreads();
  const float4* wr = reinterpret_cast<const float4*>(wo_w + (size_t)tid * DD);
  const float4* pp = reinterpret_cast<const float4*>(pe);
  float acc = 0.f;
#pragma unroll 8
  for (int k = 0; k < 64; ++k) {
    float4 w4 = wr[k]; float4 p4 = pp[k];
    acc = fmaf(w4.x, p4.x, acc);
    acc = fmaf(w4.y, p4.y, acc);
    acc = fmaf(w4.z, p4.z, acc);
    acc = fmaf(w4.w, p4.w, acc);
  }
  att_r[(size_t)t*DD + tid] = acc + wo_b[tid];
}

// ---- kernel 2 (MFMA bf16x3, round-21 verified): att_x = x^T @ wv_w^T + b ----
// grid (4 sT, 2 dT, 64 b) = 512 blocks, block 256 (4 waves). Tile 64s x 128d.
__global__ __launch_bounds__(256) void k_attx(
    const float* __restrict__ x, const float* __restrict__ wv_w,
    const float* __restrict__ wv_b, float* __restrict__ att_x)
{
  const int b   = blockIdx.z;
  const int dT  = blockIdx.y;
  const int s0  = blockIdx.x * 64;
  const int d0  = dT * 128;
  const int tid = threadIdx.x;
  const int lane = tid & 63;
  const int wid  = tid >> 6;
  const float* xb = x + (size_t)b * DD * SS;   // [c][s]

  __shared__ float xls[32 * 65];               // fp32 [c][s] pad 65
  __shared__ unsigned short wbh[128 * 32];     // bf16 hi
  __shared__ unsigned short wbl[128 * 32];     // bf16 lo

  f32x4 acc[8];
#pragma unroll
  for (int dt = 0; dt < 8; ++dt) acc[dt] = (f32x4){0.f, 0.f, 0.f, 0.f};

  const int dl = tid >> 1, kh = tid & 1;
  const float* wsrc = wv_w + (size_t)(d0 + dl) * DD + kh * 16;
  const int cl = tid >> 3, sq = (tid & 7) * 8;
  const float* xsrc = xb + (size_t)cl * SS + s0 + sq;

  float4 wr0, wr1, wr2, wr3, xr0, xr1;
  wr0 = *reinterpret_cast<const float4*>(wsrc);
  wr1 = *reinterpret_cast<const float4*>(wsrc + 4);
  wr2 = *reinterpret_cast<const float4*>(wsrc + 8);
  wr3 = *reinterpret_cast<const float4*>(wsrc + 12);
  xr0 = *reinterpret_cast<const float4*>(xsrc);
  xr1 = *reinterpret_cast<const float4*>(xsrc + 4);

  for (int cc = 0; cc < 8; ++cc) {
    __syncthreads();
    {
      const float wf[16] = {wr0.x, wr0.y, wr0.z, wr0.w, wr1.x, wr1.y, wr1.z, wr1.w,
                            wr2.x, wr2.y, wr2.z, wr2.w, wr3.x, wr3.y, wr3.z, wr3.w};
      const int dt = dl >> 4, dcol = dl & 15;
#pragma unroll
      for (int g2 = 0; g2 < 2; ++g2) {
        const int kg = kh * 2 + g2;
        unsigned hp[4], lp[4];
#pragma unroll
        for (int p = 0; p < 4; ++p) {
          float fa = wf[g2 * 8 + p * 2], fb = wf[g2 * 8 + p * 2 + 1];
          unsigned ua = __float_as_uint(fa), ub = __float_as_uint(fb);
          hp[p] = (ua >> 16) | (ub & 0xffff0000u);
          float la = fa - __uint_as_float(ua & 0xffff0000u);
          float lb = fb - __uint_as_float(ub & 0xffff0000u);
          lp[p] = (__float_as_uint(la) >> 16) | (__float_as_uint(lb) & 0xffff0000u);
        }
        const int base = ((dt * 4 + kg) * 16 + dcol) * 8;
        *reinterpret_cast<uint4*>(&wbh[base]) = make_uint4(hp[0], hp[1], hp[2], hp[3]);
        *reinterpret_cast<uint4*>(&wbl[base]) = make_uint4(lp[0], lp[1], lp[2], lp[3]);
      }
    }
    {
      float* xd = &xls[cl * 65 + sq];
      xd[0] = xr0.x; xd[1] = xr0.y; xd[2] = xr0.z; xd[3] = xr0.w;
      xd[4] = xr1.x; xd[5] = xr1.y; xd[6] = xr1.z; xd[7] = xr1.w;
    }
    if (cc < 7) {
      const float* wn = wsrc + (size_t)(cc + 1) * 32;
      wr0 = *reinterpret_cast<const float4*>(wn);
      wr1 = *reinterpret_cast<const float4*>(wn + 4);
      wr2 = *reinterpret_cast<const float4*>(wn + 8);
      wr3 = *reinterpret_cast<const float4*>(wn + 12);
      const float* xn = xsrc + (size_t)(cc + 1) * 32 * SS;
      xr0 = *reinterpret_cast<const float4*>(xn);
      xr1 = *reinterpret_cast<const float4*>(xn + 4);
    }
    __syncthreads();
    const int g = lane >> 4;
    const int sA = wid * 16 + (lane & 15);
    union { bf16x8 v; unsigned short u[8]; } ah, al;
#pragma unroll
    for (int j = 0; j < 8; ++j) {
      float f = xls[(g * 8 + j) * 65 + sA];
      unsigned u = __float_as_uint(f);
      ah.u[j] = (unsigned short)(u >> 16);
      float fl = f - __uint_as_float(u & 0xffff0000u);
      al.u[j] = (unsigned short)(__float_as_uint(fl) >> 16);
    }
#pragma unroll
    for (int dt = 0; dt < 8; ++dt) {
      const int base = ((dt * 4 + g) * 16 + (lane & 15)) * 8;
      bf16x8 bh = *reinterpret_cast<const bf16x8*>(&wbh[base]);
      bf16x8 bl = *reinterpret_cast<const bf16x8*>(&wbl[base]);
      acc[dt] = __builtin_amdgcn_mfma_f32_16x16x32_bf16(ah.v, bh, acc[dt], 0, 0, 0);
      acc[dt] = __builtin_amdgcn_mfma_f32_16x16x32_bf16(ah.v, bl, acc[dt], 0, 0, 0);
      acc[dt] = __builtin_amdgcn_mfma_f32_16x16x32_bf16(al.v, bh, acc[dt], 0, 0, 0);
    }
  }

  const int dcol = lane & 15, rg = lane >> 4;
#pragma unroll
  for (int dt = 0; dt < 8; ++dt) {
    const int d = d0 + dt * 16 + dcol;
    float bv = wv_b[d];
#pragma unroll
    for (int r = 0; r < 4; ++r) {
      const int s = s0 + wid * 16 + rg * 4 + r;
      att_x[((size_t)(b * SS + s)) * DD + d] = acc[dt][r] + bv;
    }
  }
}

// ---- kernel 3 (MERGED v7): scores + softmax + out, 512-thread blocks (2/CU) ----
// grid (64 b, 4 tq), block 512.  Thread (sl=tid>>3, c=tid&7 owns 32 d).
// Factored exp (round-21 verified math); ea layout c-stride-40 (2-way alias, free).
__global__ __launch_bounds__(512, 2) void k_score_out(
    const float* __restrict__ att_x, const float* __restrict__ att_r,
    const float* __restrict__ we_w, float* __restrict__ out, int T)
{
  const int b  = blockIdx.x;
  const int tq = blockIdx.y;
  const int tchunk = (T + 3) >> 2;      // <= 8
  const int t0 = tq * tchunk;
  const int nT = (T - t0 < tchunk) ? (T - t0) : tchunk;
  if (nT <= 0) return;
  const int tid = threadIdx.x;

  __shared__ float pool[4096];          // ea [tl][c*40 + dd] (Phase A) / red[4][4][256] (Phase B)
  __shared__ float scS[8 * 256];        // scores -> alpha (in place)
  __shared__ float mred[8][4];
  __shared__ float sred[8][4];

  // ---- stage ea = exp2(K2*att_r); zero scS ----
  for (int idx = tid; idx < nT * 256; idx += 512) {
    int tl = idx >> 8, d = idx & 255;
    pool[tl * 320 + (d >> 5) * 40 + (d & 31)] = EXP2(att_r[(size_t)(t0 + tl) * DD + d] * K2);
  }
  for (int idx = tid; idx < 8 * 256; idx += 512) scS[idx] = 0.f;

  const int sl = tid >> 3;       // 0..63
  const int c  = tid & 7;        // 0..7 -> d in [c*32, c*32+32)
  float4 w0, w1, w2, w3, w4, w5, w6, w7;
  {
    const float4* we4 = reinterpret_cast<const float4*>(we_w + c * 32);
    w0 = we4[0]; w1 = we4[1]; w2 = we4[2]; w3 = we4[3];
    w4 = we4[4]; w5 = we4[5]; w6 = we4[6]; w7 = we4[7];
  }
  __syncthreads();

  // ---- Phase A: raw scores, 4 s-quarter passes; frag = ef = exp2(K2*att_x), 32/thread ----
#pragma unroll
  for (int q = 0; q < 4; ++q) {
    const int s = q * 64 + sl;
    float4 f0, f1, f2, f3, f4, f5, f6, f7;
    {
      const float4* ax4 = reinterpret_cast<const float4*>(
          att_x + ((size_t)(b * SS + s)) * DD + c * 32);
      f0 = ax4[0]; f1 = ax4[1]; f2 = ax4[2]; f3 = ax4[3];
      f4 = ax4[4]; f5 = ax4[5]; f6 = ax4[6]; f7 = ax4[7];
#define EXPV(F) F.x = EXP2(F.x*K2); F.y = EXP2(F.y*K2); F.z = EXP2(F.z*K2); F.w = EXP2(F.w*K2)
      EXPV(f0); EXPV(f1); EXPV(f2); EXPV(f3);
      EXPV(f4); EXPV(f5); EXPV(f6); EXPV(f7);
#undef EXPV
    }
#pragma unroll 2
    for (int tl = 0; tl < nT; ++tl) {
      const float* aS = &pool[tl * 320 + c * 40];
      float p0 = 0.f, p1 = 0.f, p2 = 0.f, p3 = 0.f;
#define TERM4(P, F, KK) do {                                               \
      float4 a4 = *reinterpret_cast<const float4*>(aS + (KK) * 4);         \
      P = fmaf(w##KK.x, fast_rcp(fmaf(F.x, a4.x, 1.f)), P);                \
      P = fmaf(w##KK.y, fast_rcp(fmaf(F.y, a4.y, 1.f)), P);                \
      P = fmaf(w##KK.z, fast_rcp(fmaf(F.z, a4.z, 1.f)), P);                \
      P = fmaf(w##KK.w, fast_rcp(fmaf(F.w, a4.w, 1.f)), P);                \
    } while (0)
      TERM4(p0, f0, 0); TERM4(p1, f1, 1); TERM4(p2, f2, 2); TERM4(p3, f3, 3);
      TERM4(p0, f4, 4); TERM4(p1, f5, 5); TERM4(p2, f6, 6); TERM4(p3, f7, 7);
#undef TERM4
      float part = (p0 + p1) + (p2 + p3);
      // reduce over c (lane bits 0..2)
      part += __shfl_xor(part, 1);
      part += __shfl_xor(part, 2);
      part += __shfl_xor(part, 4);
      if (c == 0) scS[tl * 256 + s] = -2.f * part;  // + softmax-invariant const (dropped)
    }
  }
  __syncthreads();

  // ---- softmax over s: 4 passes x 2 rows (row r = pass*2 + (tid>>8)) ----
  const int d   = tid & 255;
  const int h2  = tid >> 8;      // 0..1
  const int wv4 = (tid >> 6) & 3;
#pragma unroll
  for (int pass = 0; pass < 4; ++pass) {
    const int r = pass * 2 + h2;        // 0..7
    const bool live = (r < nT);
    float v = live ? scS[r * 256 + d] : -3.0e38f;
    float m = v;
    m = fmaxf(m, __shfl_xor(m, 1));
    m = fmaxf(m, __shfl_xor(m, 2));
    m = fmaxf(m, __shfl_xor(m, 4));
    m = fmaxf(m, __shfl_xor(m, 8));
    m = fmaxf(m, __shfl_xor(m, 16));
    m = fmaxf(m, __shfl_xor(m, 32));
    if ((tid & 63) == 0) mred[r][wv4] = m;
    __syncthreads();
    float M = fmaxf(fmaxf(mred[r][0], mred[r][1]), fmaxf(mred[r][2], mred[r][3]));
    float ev = live ? EXP2((v - M) * LOG2E) : 0.f;
    float ss = ev;
    ss += __shfl_xor(ss, 1);
    ss += __shfl_xor(ss, 2);
    ss += __shfl_xor(ss, 4);
    ss += __shfl_xor(ss, 8);
    ss += __shfl_xor(ss, 16);
    ss += __shfl_xor(ss, 32);
    if ((tid & 63) == 0) sred[r][wv4] = ss;
    __syncthreads();
    float S = sred[r][0] + sred[r][1] + sred[r][2] + sred[r][3];
    if (live) scS[r * 256 + d] = ev * fast_rcp(S);
  }
  __syncthreads();     // pool-as-ea dead; pool becomes red

  // ---- Phase B: out = (1/256)*sum_s alpha*att_x; subs cover scg = sub*2 + h2 ----
#pragma unroll
  for (int half = 0; half < 2; ++half) {
    const int nR = (nT - half * 4 < 4) ? (nT - half * 4) : 4;
#pragma unroll
    for (int sub = 0; sub < 2; ++sub) {
      const int scg = sub * 2 + h2;     // 0..3
      float v[64];
      const float* ax = att_x + ((size_t)(b * SS) + scg * 64) * DD + d;
#pragma unroll
      for (int i = 0; i < 64; ++i) v[i] = ax[(size_t)i * DD];
#pragma unroll
      for (int tl = 0; tl < 4; ++tl) {
        float a = 0.f;
#pragma unroll
        for (int i4 = 0; i4 < 16; ++i4) {
          float4 a4 = *reinterpret_cast<const float4*>(
              &scS[(half * 4 + tl) * 256 + scg * 64 + i4 * 4]);   // wave-uniform
          a = fmaf(a4.x, v[i4*4+0], a);
          a = fmaf(a4.y, v[i4*4+1], a);
          a = fmaf(a4.z, v[i4*4+2], a);
          a = fmaf(a4.w, v[i4*4+3], a);
        }
        pool[scg * 1024 + tl * 256 + d] = a;       // pool-as-red
      }
    }
    __syncthreads();
    for (int idx = tid; idx < nR * 256; idx += 512) {
      float sum = pool[idx] + pool[1024 + idx] + pool[2048 + idx] + pool[3072 + idx];
      out[((size_t)b * T + t0 + half * 4) * SS + idx] = sum * (1.0f / 256.0f);
    }
    __syncthreads();
  }
}

extern "C" void kernel_launch(void* const* d_in, const int* in_sizes, int n_in,
                              void* d_out, int out_size, void* d_ws, size_t ws_size,
                              hipStream_t stream) {
  (void)in_sizes; (void)n_in; (void)ws_size;
  const float* x    = (const float*)d_in[0];
  // d_in[1] = seq_len (device int scalar) -- T derived from out_size instead
  const float* wo_w = (const float*)d_in[2];
  const float* wo_b = (const float*)d_in[3];
  const float* wv_w = (const float*)d_in[4];
  const float* wv_b = (const float*)d_in[5];
  const float* we_w = (const float*)d_in[6];
  float* out = (float*)d_out;
  const int T = out_size / (BB * DD);

  float* att_x = (float*)d_ws;                     // 64*256*256 floats (16 MB)
  float* att_r = att_x + (size_t)BB * SS * DD;     // T*DD floats

  k_prep      <<<dim3(T), 256, 0, stream>>>(wo_w, wo_b, att_r, T);
  k_attx      <<<dim3(4, 2, BB), 256, 0, stream>>>(x, wv_w, wv_b, att_x);
  k_score_out <<<dim3(BB, 4), 512, 0, stream>>>(att_x, att_r, we_w, out, T);
}

// Round 24
// 55.439 us; speedup vs baseline: 1.2035x; 1.2035x over previous
//
#include <hip/hip_runtime.h>

#define DD 256
#define BB 64
#define SS 256                       // H*W
#define K2 2.8853900817779268f      // 2*log2(e)
#define LOG2E 1.4426950408889634f

#if __has_builtin(__builtin_amdgcn_exp2f)
#define EXP2(x) __builtin_amdgcn_exp2f(x)
#else
#define EXP2(x) exp2f(x)
#endif

typedef __attribute__((ext_vector_type(8))) short bf16x8;
typedef __attribute__((ext_vector_type(4))) float f32x4;

static __device__ __forceinline__ float fast_rcp(float x) {
  return __builtin_amdgcn_rcpf(x);
}

// ---- kernel 1: blocks 0..7 convert wv_w -> bf16 hi/lo in MFMA-B order (R22-verified);
//      blocks 8..8+T: att_r = pe@wo^T + b ----
// whi/wlo layout: slot = dt16*64 + kg*16 + dcol; addr = (cc*1024 + slot)*8 + j
//   == bf16 parts of wv_w[dt16*16+dcol][cc*32+kg*8+j]   (1 slot == 1 uint4)
__global__ __launch_bounds__(256) void k_prep(
    const float* __restrict__ wv_w,
    const float* __restrict__ wo_w, const float* __restrict__ wo_b,
    unsigned short* __restrict__ whi, unsigned short* __restrict__ wlo,
    float* __restrict__ att_r, int T)
{
  const int tid = threadIdx.x;
  if (blockIdx.x < 8) {
    const int cc = blockIdx.x;
#pragma unroll
    for (int sl = 0; sl < 4; ++sl) {
      const int slot = sl * 256 + tid;     // 0..1023
      const int dt16 = slot >> 6;          // 0..15
      const int kg   = (slot >> 4) & 3;
      const int dcol = slot & 15;
      const int d  = dt16 * 16 + dcol;
      const int c0 = cc * 32 + kg * 8;
      float4 a = *reinterpret_cast<const float4*>(wv_w + (size_t)d * DD + c0);
      float4 b4 = *reinterpret_cast<const float4*>(wv_w + (size_t)d * DD + c0 + 4);
      const float wf[8] = {a.x, a.y, a.z, a.w, b4.x, b4.y, b4.z, b4.w};
      unsigned hp[4], lp[4];
#pragma unroll
      for (int p = 0; p < 4; ++p) {
        float fa = wf[p * 2], fb = wf[p * 2 + 1];
        unsigned ua = __float_as_uint(fa), ub = __float_as_uint(fb);
        hp[p] = (ua >> 16) | (ub & 0xffff0000u);
        float la = fa - __uint_as_float(ua & 0xffff0000u);
        float lb = fb - __uint_as_float(ub & 0xffff0000u);
        lp[p] = (__float_as_uint(la) >> 16) | (__float_as_uint(lb) & 0xffff0000u);
      }
      const size_t base = ((size_t)cc * 1024 + slot) * 8;
      *reinterpret_cast<uint4*>(whi + base) = make_uint4(hp[0], hp[1], hp[2], hp[3]);
      *reinterpret_cast<uint4*>(wlo + base) = make_uint4(lp[0], lp[1], lp[2], lp[3]);
    }
    return;
  }
  // ---- att_r branch ----
  const int t = blockIdx.x - 8;
  if (t >= T) return;
  __shared__ float pe[DD];
  {
    int i = tid >> 1;
    double r = pow(10000.0, -(double)(2*i) / 256.0);
    double ang = (double)t * r;
    pe[tid] = (float)((tid & 1) ? cos(ang) : sin(ang));
  }
  __syncthreads();
  const float4* wr = reinterpret_cast<const float4*>(wo_w + (size_t)tid * DD);
  const float4* pp = reinterpret_cast<const float4*>(pe);
  float acc = 0.f;
#pragma unroll 8
  for (int k = 0; k < 64; ++k) {
    float4 w4 = wr[k]; float4 p4 = pp[k];
    acc = fmaf(w4.x, p4.x, acc);
    acc = fmaf(w4.y, p4.y, acc);
    acc = fmaf(w4.z, p4.z, acc);
    acc = fmaf(w4.w, p4.w, acc);
  }
  att_r[(size_t)t*DD + tid] = acc + wo_b[tid];
}

// ---- kernel 2 (MFMA v8): att_x = x^T @ wv_w^T + b ----
// grid (4 sT, 2 dT, 64 b) = 512 blocks, block 256 (4 waves). Tile 64s x 128d.
// w staged from PRECOMPUTED whi/wlo: the dT-half of chunk cc is 512 contiguous
// uint4 at whi4[cc*1024 + dT*512] -> 2 coalesced uint4 copies/thread, no VALU.
// x staged fp32 [c][s] pad-65 (R21-verified). Compute identical to R21.
__global__ __launch_bounds__(256) void k_attx(
    const float* __restrict__ x,
    const unsigned short* __restrict__ whi, const unsigned short* __restrict__ wlo,
    const float* __restrict__ wv_b, float* __restrict__ att_x)
{
  const int b   = blockIdx.z;
  const int dT  = blockIdx.y;
  const int s0  = blockIdx.x * 64;
  const int d0  = dT * 128;
  const int tid = threadIdx.x;
  const int lane = tid & 63;
  const int wid  = tid >> 6;
  const float* xb = x + (size_t)b * DD * SS;   // [c][s]
  const uint4* whi4 = reinterpret_cast<const uint4*>(whi);
  const uint4* wlo4 = reinterpret_cast<const uint4*>(wlo);

  __shared__ float xls[32 * 65];               // fp32 [c][s] pad 65
  __shared__ uint4 wbh4[512];                  // bf16 hi, slot-per-uint4 (8 KB)
  __shared__ uint4 wbl4[512];                  // bf16 lo (8 KB)

  f32x4 acc[8];
#pragma unroll
  for (int dt = 0; dt < 8; ++dt) acc[dt] = (f32x4){0.f, 0.f, 0.f, 0.f};

  const int cl = tid >> 3, sq = (tid & 7) * 8;
  const float* xsrc = xb + (size_t)cl * SS + s0 + sq;
  const int wofs = dT * 512;                   // uint4 offset of this half within a chunk

  uint4 wh0, wh1, wl0, wl1;
  float4 xr0, xr1;
  wh0 = whi4[wofs + tid];
  wh1 = whi4[wofs + 256 + tid];
  wl0 = wlo4[wofs + tid];
  wl1 = wlo4[wofs + 256 + tid];
  xr0 = *reinterpret_cast<const float4*>(xsrc);
  xr1 = *reinterpret_cast<const float4*>(xsrc + 4);

  for (int cc = 0; cc < 8; ++cc) {
    __syncthreads();                           // previous compute done; LDS free
    wbh4[tid]       = wh0;
    wbh4[256 + tid] = wh1;
    wbl4[tid]       = wl0;
    wbl4[256 + tid] = wl1;
    {
      float* xd = &xls[cl * 65 + sq];
      xd[0] = xr0.x; xd[1] = xr0.y; xd[2] = xr0.z; xd[3] = xr0.w;
      xd[4] = xr1.x; xd[5] = xr1.y; xd[6] = xr1.z; xd[7] = xr1.w;
    }
    if (cc < 7) {                              // prefetch next chunk -> regs
      const int cb = (cc + 1) * 1024 + wofs;
      wh0 = whi4[cb + tid];
      wh1 = whi4[cb + 256 + tid];
      wl0 = wlo4[cb + tid];
      wl1 = wlo4[cb + 256 + tid];
      const float* xn = xsrc + (size_t)(cc + 1) * 32 * SS;
      xr0 = *reinterpret_cast<const float4*>(xn);
      xr1 = *reinterpret_cast<const float4*>(xn + 4);
    }
    __syncthreads();                           // LDS ready
    const int g = lane >> 4;
    const int sA = wid * 16 + (lane & 15);
    union { bf16x8 v; unsigned short u[8]; } ah, al;
#pragma unroll
    for (int j = 0; j < 8; ++j) {
      float f = xls[(g * 8 + j) * 65 + sA];
      unsigned u = __float_as_uint(f);
      ah.u[j] = (unsigned short)(u >> 16);
      float fl = f - __uint_as_float(u & 0xffff0000u);
      al.u[j] = (unsigned short)(__float_as_uint(fl) >> 16);
    }
#pragma unroll
    for (int dt = 0; dt < 8; ++dt) {
      const int slot = (dt * 4 + g) * 16 + (lane & 15);   // local slot in half-chunk
      bf16x8 bh = *reinterpret_cast<const bf16x8*>(&wbh4[slot]);
      bf16x8 bl = *reinterpret_cast<const bf16x8*>(&wbl4[slot]);
      acc[dt] = __builtin_amdgcn_mfma_f32_16x16x32_bf16(ah.v, bh, acc[dt], 0, 0, 0);
      acc[dt] = __builtin_amdgcn_mfma_f32_16x16x32_bf16(ah.v, bl, acc[dt], 0, 0, 0);
      acc[dt] = __builtin_amdgcn_mfma_f32_16x16x32_bf16(al.v, bh, acc[dt], 0, 0, 0);
    }
  }

  // ---- epilogue: bias + store.  C/D: col(d)=lane&15, row(s)=(lane>>4)*4+r ----
  const int dcol = lane & 15, rg = lane >> 4;
#pragma unroll
  for (int dt = 0; dt < 8; ++dt) {
    const int d = d0 + dt * 16 + dcol;
    float bv = wv_b[d];
#pragma unroll
    for (int r = 0; r < 4; ++r) {
      const int s = s0 + wid * 16 + rg * 4 + r;
      att_x[((size_t)(b * SS + s)) * DD + d] = acc[dt][r] + bv;
    }
  }
}

// ---- kernel 3 (MERGED v6, round-21 verified): scores + softmax + out ----
// grid (64 b, 4 tq), block 1024.  Factored exp: ea(t,d) staged, ef(s,d) in regs.
__global__ __launch_bounds__(1024, 2) void k_score_out(
    const float* __restrict__ att_x, const float* __restrict__ att_r,
    const float* __restrict__ we_w, float* __restrict__ out, int T)
{
  const int b  = blockIdx.x;
  const int tq = blockIdx.y;
  const int tchunk = (T + 3) >> 2;      // <= 8
  const int t0 = tq * tchunk;
  const int nT = (T - t0 < tchunk) ? (T - t0) : tchunk;
  if (nT <= 0) return;
  const int tid = threadIdx.x;

  __shared__ float pool[4096];          // attrS-as-ea (Phase A) / red (Phase B)
  __shared__ float scS[8 * 256];        // scores -> alpha (in place)
  __shared__ float mred[8][4];
  __shared__ float sred[8][4];

  for (int idx = tid; idx < nT * 256; idx += 1024) {
    int tl = idx >> 8, d = idx & 255;
    pool[tl * 320 + (d >> 4) * 20 + (d & 15)] = EXP2(att_r[(size_t)(t0 + tl) * DD + d] * K2);
  }
  for (int idx = tid; idx < 8 * 256; idx += 1024) scS[idx] = 0.f;

  const int sl = tid >> 4;       // 0..63
  const int c  = tid & 15;       // 0..15
  float4 w0, w1, w2, w3;
  {
    const float4* we4 = reinterpret_cast<const float4*>(we_w + c * 16);
    w0 = we4[0]; w1 = we4[1]; w2 = we4[2]; w3 = we4[3];
  }
  __syncthreads();

#pragma unroll
  for (int q = 0; q < 4; ++q) {
    const int s = q * 64 + sl;
    float f0x, f0y, f0z, f0w, f1x, f1y, f1z, f1w;
    float f2x, f2y, f2z, f2w, f3x, f3y, f3z, f3w;
    {
      const float4* ax4 = reinterpret_cast<const float4*>(
          att_x + ((size_t)(b * SS + s)) * DD + c * 16);
      float4 a = ax4[0], bq = ax4[1], cq = ax4[2], dq = ax4[3];
      f0x = EXP2(a.x*K2);  f0y = EXP2(a.y*K2);  f0z = EXP2(a.z*K2);  f0w = EXP2(a.w*K2);
      f1x = EXP2(bq.x*K2); f1y = EXP2(bq.y*K2); f1z = EXP2(bq.z*K2); f1w = EXP2(bq.w*K2);
      f2x = EXP2(cq.x*K2); f2y = EXP2(cq.y*K2); f2z = EXP2(cq.z*K2); f2w = EXP2(cq.w*K2);
      f3x = EXP2(dq.x*K2); f3y = EXP2(dq.y*K2); f3z = EXP2(dq.z*K2); f3w = EXP2(dq.w*K2);
    }
#pragma unroll 2
    for (int tl = 0; tl < nT; ++tl) {
      const float* aS = &pool[tl * 320 + c * 20];
      float4 a0 = *reinterpret_cast<const float4*>(aS);
      float4 a1 = *reinterpret_cast<const float4*>(aS + 4);
      float4 a2 = *reinterpret_cast<const float4*>(aS + 8);
      float4 a3 = *reinterpret_cast<const float4*>(aS + 12);
      float p0 = 0.f, p1 = 0.f, p2 = 0.f, p3 = 0.f;
      p0 = fmaf(w0.x, fast_rcp(fmaf(f0x, a0.x, 1.f)), p0);
      p0 = fmaf(w0.y, fast_rcp(fmaf(f0y, a0.y, 1.f)), p0);
      p0 = fmaf(w0.z, fast_rcp(fmaf(f0z, a0.z, 1.f)), p0);
      p0 = fmaf(w0.w, fast_rcp(fmaf(f0w, a0.w, 1.f)), p0);
      p1 = fmaf(w1.x, fast_rcp(fmaf(f1x, a1.x, 1.f)), p1);
      p1 = fmaf(w1.y, fast_rcp(fmaf(f1y, a1.y, 1.f)), p1);
      p1 = fmaf(w1.z, fast_rcp(fmaf(f1z, a1.z, 1.f)), p1);
      p1 = fmaf(w1.w, fast_rcp(fmaf(f1w, a1.w, 1.f)), p1);
      p2 = fmaf(w2.x, fast_rcp(fmaf(f2x, a2.x, 1.f)), p2);
      p2 = fmaf(w2.y, fast_rcp(fmaf(f2y, a2.y, 1.f)), p2);
      p2 = fmaf(w2.z, fast_rcp(fmaf(f2z, a2.z, 1.f)), p2);
      p2 = fmaf(w2.w, fast_rcp(fmaf(f2w, a2.w, 1.f)), p2);
      p3 = fmaf(w3.x, fast_rcp(fmaf(f3x, a3.x, 1.f)), p3);
      p3 = fmaf(w3.y, fast_rcp(fmaf(f3y, a3.y, 1.f)), p3);
      p3 = fmaf(w3.z, fast_rcp(fmaf(f3z, a3.z, 1.f)), p3);
      p3 = fmaf(w3.w, fast_rcp(fmaf(f3w, a3.w, 1.f)), p3);
      float part = (p0 + p1) + (p2 + p3);
      part += __shfl_xor(part, 1);
      part += __shfl_xor(part, 2);
      part += __shfl_xor(part, 4);
      part += __shfl_xor(part, 8);
      if (c == 0) scS[tl * 256 + s] = -2.f * part;  // + softmax-invariant const (dropped)
    }
  }
  __syncthreads();

  const int d   = tid & 255;
  const int scg = tid >> 8;   // 0..3
  const int wv4 = d >> 6;
#pragma unroll
  for (int pass = 0; pass < 2; ++pass) {
    const int r = pass * 4 + scg;       // 0..7
    const bool live = (r < nT);
    float v = live ? scS[r * 256 + d] : -3.0e38f;
    float m = v;
    m = fmaxf(m, __shfl_xor(m, 1));
    m = fmaxf(m, __shfl_xor(m, 2));
    m = fmaxf(m, __shfl_xor(m, 4));
    m = fmaxf(m, __shfl_xor(m, 8));
    m = fmaxf(m, __shfl_xor(m, 16));
    m = fmaxf(m, __shfl_xor(m, 32));
    if ((tid & 63) == 0) mred[r][wv4] = m;
    __syncthreads();
    float M = fmaxf(fmaxf(mred[r][0], mred[r][1]), fmaxf(mred[r][2], mred[r][3]));
    float ev = live ? EXP2((v - M) * LOG2E) : 0.f;
    float ss = ev;
    ss += __shfl_xor(ss, 1);
    ss += __shfl_xor(ss, 2);
    ss += __shfl_xor(ss, 4);
    ss += __shfl_xor(ss, 8);
    ss += __shfl_xor(ss, 16);
    ss += __shfl_xor(ss, 32);
    if ((tid & 63) == 0) sred[r][wv4] = ss;
    __syncthreads();
    float S = sred[r][0] + sred[r][1] + sred[r][2] + sred[r][3];
    if (live) scS[r * 256 + d] = ev * fast_rcp(S);
  }
  __syncthreads();     // pool-as-ea dead; pool becomes red

  float v[64];
  const float* ax = att_x + ((size_t)(b * SS) + scg * 64) * DD + d;
#pragma unroll
  for (int i = 0; i < 64; ++i) v[i] = ax[(size_t)i * DD];

#pragma unroll
  for (int half = 0; half < 2; ++half) {
    const int nR = (nT - half * 4 < 4) ? (nT - half * 4) : 4;
#pragma unroll
    for (int tl = 0; tl < 4; ++tl) {
      float a = 0.f;
#pragma unroll
      for (int i4 = 0; i4 < 16; ++i4) {
        float4 a4 = *reinterpret_cast<const float4*>(
            &scS[(half * 4 + tl) * 256 + scg * 64 + i4 * 4]);   // wave-uniform
        a = fmaf(a4.x, v[i4*4+0], a);
        a = fmaf(a4.y, v[i4*4+1], a);
        a = fmaf(a4.z, v[i4*4+2], a);
        a = fmaf(a4.w, v[i4*4+3], a);
      }
      pool[scg * 1024 + tl * 256 + d] = a;       // pool-as-red
    }
    __syncthreads();
    for (int idx = tid; idx < nR * 256; idx += 1024) {
      float sum = pool[idx] + pool[1024 + idx] + pool[2048 + idx] + pool[3072 + idx];
      out[((size_t)b * T + t0 + half * 4) * SS + idx] = sum * (1.0f / 256.0f);
    }
    __syncthreads();
  }
}

extern "C" void kernel_launch(void* const* d_in, const int* in_sizes, int n_in,
                              void* d_out, int out_size, void* d_ws, size_t ws_size,
                              hipStream_t stream) {
  (void)in_sizes; (void)n_in; (void)ws_size;
  const float* x    = (const float*)d_in[0];
  // d_in[1] = seq_len (device int scalar) -- T derived from out_size instead
  const float* wo_w = (const float*)d_in[2];
  const float* wo_b = (const float*)d_in[3];
  const float* wv_w = (const float*)d_in[4];
  const float* wv_b = (const float*)d_in[5];
  const float* we_w = (const float*)d_in[6];
  float* out = (float*)d_out;
  const int T = out_size / (BB * DD);

  float* att_x = (float*)d_ws;                           // 64*256*256 floats (16 MB)
  float* att_r = att_x + (size_t)BB * SS * DD;           // T*DD floats
  unsigned short* whi = (unsigned short*)(att_r + 32 * DD);   // 65536 shorts (128 KB)
  unsigned short* wlo = whi + 65536;                          // 65536 shorts (128 KB)

  k_prep      <<<dim3(8 + T), 256, 0, stream>>>(wv_w, wo_w, wo_b, whi, wlo, att_r, T);
  k_attx      <<<dim3(4, 2, BB), 256, 0, stream>>>(x, whi, wlo, wv_b, att_x);
  k_score_out <<<dim3(BB, 4), 1024, 0, stream>>>(att_x, att_r, we_w, out, T);
}

// Round 25
// 54.577 us; speedup vs baseline: 1.2226x; 1.0158x over previous
//
#include <hip/hip_runtime.h>

#define DD 256
#define BB 64
#define SS 256                       // H*W
#define K2 2.8853900817779268f      // 2*log2(e)
#define LOG2E 1.4426950408889634f

#if __has_builtin(__builtin_amdgcn_exp2f)
#define EXP2(x) __builtin_amdgcn_exp2f(x)
#else
#define EXP2(x) exp2f(x)
#endif

typedef __attribute__((ext_vector_type(8))) short bf16x8;
typedef __attribute__((ext_vector_type(4))) float f32x4;

static __device__ __forceinline__ float fast_rcp(float x) {
  return __builtin_amdgcn_rcpf(x);
}

// ---- kernel 1: blocks 0..7 convert wv_w -> bf16 hi/lo in MFMA-B order (R22/R24-verified);
//      blocks 8..8+T: att_r = pe@wo^T + b ----
__global__ __launch_bounds__(256) void k_prep(
    const float* __restrict__ wv_w,
    const float* __restrict__ wo_w, const float* __restrict__ wo_b,
    unsigned short* __restrict__ whi, unsigned short* __restrict__ wlo,
    float* __restrict__ att_r, int T)
{
  const int tid = threadIdx.x;
  if (blockIdx.x < 8) {
    const int cc = blockIdx.x;
#pragma unroll
    for (int sl = 0; sl < 4; ++sl) {
      const int slot = sl * 256 + tid;     // 0..1023
      const int dt16 = slot >> 6;          // 0..15
      const int kg   = (slot >> 4) & 3;
      const int dcol = slot & 15;
      const int d  = dt16 * 16 + dcol;
      const int c0 = cc * 32 + kg * 8;
      float4 a = *reinterpret_cast<const float4*>(wv_w + (size_t)d * DD + c0);
      float4 b4 = *reinterpret_cast<const float4*>(wv_w + (size_t)d * DD + c0 + 4);
      const float wf[8] = {a.x, a.y, a.z, a.w, b4.x, b4.y, b4.z, b4.w};
      unsigned hp[4], lp[4];
#pragma unroll
      for (int p = 0; p < 4; ++p) {
        float fa = wf[p * 2], fb = wf[p * 2 + 1];
        unsigned ua = __float_as_uint(fa), ub = __float_as_uint(fb);
        hp[p] = (ua >> 16) | (ub & 0xffff0000u);
        float la = fa - __uint_as_float(ua & 0xffff0000u);
        float lb = fb - __uint_as_float(ub & 0xffff0000u);
        lp[p] = (__float_as_uint(la) >> 16) | (__float_as_uint(lb) & 0xffff0000u);
      }
      const size_t base = ((size_t)cc * 1024 + slot) * 8;
      *reinterpret_cast<uint4*>(whi + base) = make_uint4(hp[0], hp[1], hp[2], hp[3]);
      *reinterpret_cast<uint4*>(wlo + base) = make_uint4(lp[0], lp[1], lp[2], lp[3]);
    }
    return;
  }
  // ---- att_r branch ----
  const int t = blockIdx.x - 8;
  if (t >= T) return;
  __shared__ float pe[DD];
  {
    int i = tid >> 1;
    double r = pow(10000.0, -(double)(2*i) / 256.0);
    double ang = (double)t * r;
    pe[tid] = (float)((tid & 1) ? cos(ang) : sin(ang));
  }
  __syncthreads();
  const float4* wr = reinterpret_cast<const float4*>(wo_w + (size_t)tid * DD);
  const float4* pp = reinterpret_cast<const float4*>(pe);
  float acc = 0.f;
#pragma unroll 8
  for (int k = 0; k < 64; ++k) {
    float4 w4 = wr[k]; float4 p4 = pp[k];
    acc = fmaf(w4.x, p4.x, acc);
    acc = fmaf(w4.y, p4.y, acc);
    acc = fmaf(w4.z, p4.z, acc);
    acc = fmaf(w4.w, p4.w, acc);
  }
  att_r[(size_t)t*DD + tid] = acc + wo_b[tid];
}

// ---- kernel 2 (MFMA v8, round-24 verified): att_x = x^T @ wv_w^T + b ----
// grid (4 sT, 2 dT, 64 b) = 512 blocks, block 256 (4 waves). Tile 64s x 128d.
__global__ __launch_bounds__(256) void k_attx(
    const float* __restrict__ x,
    const unsigned short* __restrict__ whi, const unsigned short* __restrict__ wlo,
    const float* __restrict__ wv_b, float* __restrict__ att_x)
{
  const int b   = blockIdx.z;
  const int dT  = blockIdx.y;
  const int s0  = blockIdx.x * 64;
  const int d0  = dT * 128;
  const int tid = threadIdx.x;
  const int lane = tid & 63;
  const int wid  = tid >> 6;
  const float* xb = x + (size_t)b * DD * SS;   // [c][s]
  const uint4* whi4 = reinterpret_cast<const uint4*>(whi);
  const uint4* wlo4 = reinterpret_cast<const uint4*>(wlo);

  __shared__ float xls[32 * 65];               // fp32 [c][s] pad 65
  __shared__ uint4 wbh4[512];                  // bf16 hi, slot-per-uint4 (8 KB)
  __shared__ uint4 wbl4[512];                  // bf16 lo (8 KB)

  f32x4 acc[8];
#pragma unroll
  for (int dt = 0; dt < 8; ++dt) acc[dt] = (f32x4){0.f, 0.f, 0.f, 0.f};

  const int cl = tid >> 3, sq = (tid & 7) * 8;
  const float* xsrc = xb + (size_t)cl * SS + s0 + sq;
  const int wofs = dT * 512;                   // uint4 offset of this half within a chunk

  uint4 wh0, wh1, wl0, wl1;
  float4 xr0, xr1;
  wh0 = whi4[wofs + tid];
  wh1 = whi4[wofs + 256 + tid];
  wl0 = wlo4[wofs + tid];
  wl1 = wlo4[wofs + 256 + tid];
  xr0 = *reinterpret_cast<const float4*>(xsrc);
  xr1 = *reinterpret_cast<const float4*>(xsrc + 4);

  for (int cc = 0; cc < 8; ++cc) {
    __syncthreads();                           // previous compute done; LDS free
    wbh4[tid]       = wh0;
    wbh4[256 + tid] = wh1;
    wbl4[tid]       = wl0;
    wbl4[256 + tid] = wl1;
    {
      float* xd = &xls[cl * 65 + sq];
      xd[0] = xr0.x; xd[1] = xr0.y; xd[2] = xr0.z; xd[3] = xr0.w;
      xd[4] = xr1.x; xd[5] = xr1.y; xd[6] = xr1.z; xd[7] = xr1.w;
    }
    if (cc < 7) {                              // prefetch next chunk -> regs
      const int cb = (cc + 1) * 1024 + wofs;
      wh0 = whi4[cb + tid];
      wh1 = whi4[cb + 256 + tid];
      wl0 = wlo4[cb + tid];
      wl1 = wlo4[cb + 256 + tid];
      const float* xn = xsrc + (size_t)(cc + 1) * 32 * SS;
      xr0 = *reinterpret_cast<const float4*>(xn);
      xr1 = *reinterpret_cast<const float4*>(xn + 4);
    }
    __syncthreads();                           // LDS ready
    const int g = lane >> 4;
    const int sA = wid * 16 + (lane & 15);
    union { bf16x8 v; unsigned short u[8]; } ah, al;
#pragma unroll
    for (int j = 0; j < 8; ++j) {
      float f = xls[(g * 8 + j) * 65 + sA];
      unsigned u = __float_as_uint(f);
      ah.u[j] = (unsigned short)(u >> 16);
      float fl = f - __uint_as_float(u & 0xffff0000u);
      al.u[j] = (unsigned short)(__float_as_uint(fl) >> 16);
    }
#pragma unroll
    for (int dt = 0; dt < 8; ++dt) {
      const int slot = (dt * 4 + g) * 16 + (lane & 15);   // local slot in half-chunk
      bf16x8 bh = *reinterpret_cast<const bf16x8*>(&wbh4[slot]);
      bf16x8 bl = *reinterpret_cast<const bf16x8*>(&wbl4[slot]);
      acc[dt] = __builtin_amdgcn_mfma_f32_16x16x32_bf16(ah.v, bh, acc[dt], 0, 0, 0);
      acc[dt] = __builtin_amdgcn_mfma_f32_16x16x32_bf16(ah.v, bl, acc[dt], 0, 0, 0);
      acc[dt] = __builtin_amdgcn_mfma_f32_16x16x32_bf16(al.v, bh, acc[dt], 0, 0, 0);
    }
  }

  // ---- epilogue: bias + store.  C/D: col(d)=lane&15, row(s)=(lane>>4)*4+r ----
  const int dcol = lane & 15, rg = lane >> 4;
#pragma unroll
  for (int dt = 0; dt < 8; ++dt) {
    const int d = d0 + dt * 16 + dcol;
    float bv = wv_b[d];
#pragma unroll
    for (int r = 0; r < 4; ++r) {
      const int s = s0 + wid * 16 + rg * 4 + r;
      att_x[((size_t)(b * SS + s)) * DD + d] = acc[dt][r] + bv;
    }
  }
}

// ---- kernel 3 (MERGED v9): scores + NO-MAX softmax + out ----
// grid (64 b, 4 tq), block 1024.  Factored exp (R21-verified Phase A);
// softmax without max-subtraction (|score| <= ~26 -> exp2 range safe),
// both rows (scg, scg+4) in ONE pass: 2 barriers instead of 4, no max butterfly.
__global__ __launch_bounds__(1024, 2) void k_score_out(
    const float* __restrict__ att_x, const float* __restrict__ att_r,
    const float* __restrict__ we_w, float* __restrict__ out, int T)
{
  const int b  = blockIdx.x;
  const int tq = blockIdx.y;
  const int tchunk = (T + 3) >> 2;      // <= 8
  const int t0 = tq * tchunk;
  const int nT = (T - t0 < tchunk) ? (T - t0) : tchunk;
  if (nT <= 0) return;
  const int tid = threadIdx.x;

  __shared__ float pool[4096];          // attrS-as-ea (Phase A) / red (Phase B)
  __shared__ float scS[8 * 256];        // scores -> alpha (in place)
  __shared__ float sred[8][4];

  for (int idx = tid; idx < nT * 256; idx += 1024) {
    int tl = idx >> 8, d = idx & 255;
    pool[tl * 320 + (d >> 4) * 20 + (d & 15)] = EXP2(att_r[(size_t)(t0 + tl) * DD + d] * K2);
  }
  for (int idx = tid; idx < 8 * 256; idx += 1024) scS[idx] = 0.f;

  const int sl = tid >> 4;       // 0..63
  const int c  = tid & 15;       // 0..15
  float4 w0, w1, w2, w3;
  {
    const float4* we4 = reinterpret_cast<const float4*>(we_w + c * 16);
    w0 = we4[0]; w1 = we4[1]; w2 = we4[2]; w3 = we4[3];
  }
  __syncthreads();

  // ---- Phase A: raw scores, 4 s-quarter passes; frag = ef = exp2(K2*att_x) ----
#pragma unroll
  for (int q = 0; q < 4; ++q) {
    const int s = q * 64 + sl;
    float f0x, f0y, f0z, f0w, f1x, f1y, f1z, f1w;
    float f2x, f2y, f2z, f2w, f3x, f3y, f3z, f3w;
    {
      const float4* ax4 = reinterpret_cast<const float4*>(
          att_x + ((size_t)(b * SS + s)) * DD + c * 16);
      float4 a = ax4[0], bq = ax4[1], cq = ax4[2], dq = ax4[3];
      f0x = EXP2(a.x*K2);  f0y = EXP2(a.y*K2);  f0z = EXP2(a.z*K2);  f0w = EXP2(a.w*K2);
      f1x = EXP2(bq.x*K2); f1y = EXP2(bq.y*K2); f1z = EXP2(bq.z*K2); f1w = EXP2(bq.w*K2);
      f2x = EXP2(cq.x*K2); f2y = EXP2(cq.y*K2); f2z = EXP2(cq.z*K2); f2w = EXP2(cq.w*K2);
      f3x = EXP2(dq.x*K2); f3y = EXP2(dq.y*K2); f3z = EXP2(dq.z*K2); f3w = EXP2(dq.w*K2);
    }
#pragma unroll 2
    for (int tl = 0; tl < nT; ++tl) {
      const float* aS = &pool[tl * 320 + c * 20];
      float4 a0 = *reinterpret_cast<const float4*>(aS);
      float4 a1 = *reinterpret_cast<const float4*>(aS + 4);
      float4 a2 = *reinterpret_cast<const float4*>(aS + 8);
      float4 a3 = *reinterpret_cast<const float4*>(aS + 12);
      float p0 = 0.f, p1 = 0.f, p2 = 0.f, p3 = 0.f;
      p0 = fmaf(w0.x, fast_rcp(fmaf(f0x, a0.x, 1.f)), p0);
      p0 = fmaf(w0.y, fast_rcp(fmaf(f0y, a0.y, 1.f)), p0);
      p0 = fmaf(w0.z, fast_rcp(fmaf(f0z, a0.z, 1.f)), p0);
      p0 = fmaf(w0.w, fast_rcp(fmaf(f0w, a0.w, 1.f)), p0);
      p1 = fmaf(w1.x, fast_rcp(fmaf(f1x, a1.x, 1.f)), p1);
      p1 = fmaf(w1.y, fast_rcp(fmaf(f1y, a1.y, 1.f)), p1);
      p1 = fmaf(w1.z, fast_rcp(fmaf(f1z, a1.z, 1.f)), p1);
      p1 = fmaf(w1.w, fast_rcp(fmaf(f1w, a1.w, 1.f)), p1);
      p2 = fmaf(w2.x, fast_rcp(fmaf(f2x, a2.x, 1.f)), p2);
      p2 = fmaf(w2.y, fast_rcp(fmaf(f2y, a2.y, 1.f)), p2);
      p2 = fmaf(w2.z, fast_rcp(fmaf(f2z, a2.z, 1.f)), p2);
      p2 = fmaf(w2.w, fast_rcp(fmaf(f2w, a2.w, 1.f)), p2);
      p3 = fmaf(w3.x, fast_rcp(fmaf(f3x, a3.x, 1.f)), p3);
      p3 = fmaf(w3.y, fast_rcp(fmaf(f3y, a3.y, 1.f)), p3);
      p3 = fmaf(w3.z, fast_rcp(fmaf(f3z, a3.z, 1.f)), p3);
      p3 = fmaf(w3.w, fast_rcp(fmaf(f3w, a3.w, 1.f)), p3);
      float part = (p0 + p1) + (p2 + p3);
      part += __shfl_xor(part, 1);
      part += __shfl_xor(part, 2);
      part += __shfl_xor(part, 4);
      part += __shfl_xor(part, 8);
      if (c == 0) scS[tl * 256 + s] = -2.f * part;  // + softmax-invariant const (dropped)
    }
  }
  __syncthreads();

  // ---- NO-MAX softmax over s: both rows (scg, scg+4) in one pass ----
  const int d   = tid & 255;
  const int scg = tid >> 8;   // 0..3
  const int wv4 = d >> 6;
  {
    const int ra = scg, rb = scg + 4;
    const bool liveA = (ra < nT), liveB = (rb < nT);
    float evA = liveA ? EXP2(scS[ra * 256 + d] * LOG2E) : 0.f;
    float evB = liveB ? EXP2(scS[rb * 256 + d] * LOG2E) : 0.f;
    float sA = evA, sB = evB;
    sA += __shfl_xor(sA, 1);  sB += __shfl_xor(sB, 1);
    sA += __shfl_xor(sA, 2);  sB += __shfl_xor(sB, 2);
    sA += __shfl_xor(sA, 4);  sB += __shfl_xor(sB, 4);
    sA += __shfl_xor(sA, 8);  sB += __shfl_xor(sB, 8);
    sA += __shfl_xor(sA, 16); sB += __shfl_xor(sB, 16);
    sA += __shfl_xor(sA, 32); sB += __shfl_xor(sB, 32);
    if ((tid & 63) == 0) { sred[ra][wv4] = sA; sred[rb][wv4] = sB; }
    __syncthreads();
    float SA = sred[ra][0] + sred[ra][1] + sred[ra][2] + sred[ra][3];
    float SB = sred[rb][0] + sred[rb][1] + sred[rb][2] + sred[rb][3];
    if (liveA) scS[ra * 256 + d] = evA * fast_rcp(SA);
    if (liveB) scS[rb * 256 + d] = evB * fast_rcp(SB);
  }
  __syncthreads();     // pool-as-ea dead; pool becomes red

  // ---- Phase B: out = (1/256)*sum_s alpha*att_x, two 4-row passes ----
  float v[64];
  const float* ax = att_x + ((size_t)(b * SS) + scg * 64) * DD + d;
#pragma unroll
  for (int i = 0; i < 64; ++i) v[i] = ax[(size_t)i * DD];

#pragma unroll
  for (int half = 0; half < 2; ++half) {
    const int nR = (nT - half * 4 < 4) ? (nT - half * 4) : 4;
#pragma unroll
    for (int tl = 0; tl < 4; ++tl) {
      float a = 0.f;
#pragma unroll
      for (int i4 = 0; i4 < 16; ++i4) {
        float4 a4 = *reinterpret_cast<const float4*>(
            &scS[(half * 4 + tl) * 256 + scg * 64 + i4 * 4]);   // wave-uniform
        a = fmaf(a4.x, v[i4*4+0], a);
        a = fmaf(a4.y, v[i4*4+1], a);
        a = fmaf(a4.z, v[i4*4+2], a);
        a = fmaf(a4.w, v[i4*4+3], a);
      }
      pool[scg * 1024 + tl * 256 + d] = a;       // pool-as-red
    }
    __syncthreads();
    for (int idx = tid; idx < nR * 256; idx += 1024) {
      float sum = pool[idx] + pool[1024 + idx] + pool[2048 + idx] + pool[3072 + idx];
      out[((size_t)b * T + t0 + half * 4) * SS + idx] = sum * (1.0f / 256.0f);
    }
    __syncthreads();
  }
}

extern "C" void kernel_launch(void* const* d_in, const int* in_sizes, int n_in,
                              void* d_out, int out_size, void* d_ws, size_t ws_size,
                              hipStream_t stream) {
  (void)in_sizes; (void)n_in; (void)ws_size;
  const float* x    = (const float*)d_in[0];
  // d_in[1] = seq_len (device int scalar) -- T derived from out_size instead
  const float* wo_w = (const float*)d_in[2];
  const float* wo_b = (const float*)d_in[3];
  const float* wv_w = (const float*)d_in[4];
  const float* wv_b = (const float*)d_in[5];
  const float* we_w = (const float*)d_in[6];
  float* out = (float*)d_out;
  const int T = out_size / (BB * DD);

  float* att_x = (float*)d_ws;                           // 64*256*256 floats (16 MB)
  float* att_r = att_x + (size_t)BB * SS * DD;           // T*DD floats
  unsigned short* whi = (unsigned short*)(att_r + 32 * DD);   // 65536 shorts (128 KB)
  unsigned short* wlo = whi + 65536;                          // 65536 shorts (128 KB)

  k_prep      <<<dim3(8 + T), 256, 0, stream>>>(wv_w, wo_w, wo_b, whi, wlo, att_r, T);
  k_attx      <<<dim3(4, 2, BB), 256, 0, stream>>>(x, whi, wlo, wv_b, att_x);
  k_score_out <<<dim3(BB, 4), 1024, 0, stream>>>(att_x, att_r, we_w, out, T);
}